// Round 1
// baseline (429.501 us; speedup 1.0000x reference)
//
#include <hip/hip_runtime.h>
#include <stdint.h>

typedef unsigned int uint;

#define NPTS 500000
#define NC 256
#define SPAIRS 600000
#define FS 14
#define F3 2744            // 14^3
#define VOXT (NC * F3)     // 702464

// ---------- helpers ----------
__device__ __forceinline__ uint encF(float f) {
    uint u = __float_as_uint(f);
    return (u & 0x80000000u) ? ~u : (u | 0x80000000u);
}
__device__ __forceinline__ float decF(uint e) {
    uint u = (e & 0x80000000u) ? (e ^ 0x80000000u) : ~e;
    return __uint_as_float(u);
}
// ids may arrive as int32 (jax x64 off) or int64; runtime flag selects.
__device__ __forceinline__ int loadId(const void* p, int i, uint is64) {
    return is64 ? (int)((const long long*)p)[i] : ((const int*)p)[i];
}

// ---------- kernel 0: init min-encodings + detect id width ----------
__global__ void k_init(const void* cids, uint* flag, uint* gmin) {
    int idx = blockIdx.x * blockDim.x + threadIdx.x;
    if (idx < NC * 3) gmin[idx] = 0xFFFFFFFFu;
    if (idx == 0) {
        // If int64: odd int32 words (high words) are 0. Sorted mid values ~128 != 0.
        const int* p = (const int*)cids;
        int z = 0;
        #pragma unroll
        for (int k = 0; k < 5; ++k) z += (p[300001 + 2 * k] == 0) ? 1 : 0;
        *flag = (z >= 3) ? 1u : 0u;
    }
}

// ---------- kernel 1: per-cluster count / sum(double) / min / max of raw coords ----------
__global__ __launch_bounds__(256) void k_stats(const void* cids, const void* pids,
        const float* coords, const uint* flagp,
        double* gsum, uint* gcnt, uint* gmin, uint* gmax) {
    __shared__ double sSum[NC][3];
    __shared__ uint   sCnt[NC];
    __shared__ uint   sMin[NC][3];
    __shared__ uint   sMax[NC][3];
    int tid = threadIdx.x;
    for (int c = tid; c < NC; c += blockDim.x) {
        sCnt[c] = 0u;
        for (int d = 0; d < 3; ++d) { sSum[c][d] = 0.0; sMin[c][d] = 0xFFFFFFFFu; sMax[c][d] = 0u; }
    }
    __syncthreads();
    uint is64 = *flagp;
    int per = (SPAIRS + gridDim.x - 1) / gridDim.x;
    int start = blockIdx.x * per;
    int end = min(start + per, SPAIRS);
    for (int s = start + tid; s < end; s += blockDim.x) {
        int cid = loadId(cids, s, is64);
        int pid = loadId(pids, s, is64);
        float x = coords[3 * pid + 0];
        float y = coords[3 * pid + 1];
        float z = coords[3 * pid + 2];
        atomicAdd(&sCnt[cid], 1u);
        atomicAdd(&sSum[cid][0], (double)x);
        atomicAdd(&sSum[cid][1], (double)y);
        atomicAdd(&sSum[cid][2], (double)z);
        atomicMin(&sMin[cid][0], encF(x)); atomicMin(&sMin[cid][1], encF(y)); atomicMin(&sMin[cid][2], encF(z));
        atomicMax(&sMax[cid][0], encF(x)); atomicMax(&sMax[cid][1], encF(y)); atomicMax(&sMax[cid][2], encF(z));
    }
    __syncthreads();
    for (int c = tid; c < NC; c += blockDim.x) {
        if (sCnt[c]) {
            atomicAdd(&gcnt[c], sCnt[c]);
            for (int d = 0; d < 3; ++d) {
                atomicAdd(&gsum[c * 3 + d], sSum[c][d]);
                atomicMin(&gmin[c * 3 + d], sMin[c][d]);
                atomicMax(&gmax[c * 3 + d], sMax[c][d]);
            }
        }
    }
}

// ---------- kernel 2: per-cluster mean/scale/offset (double) ----------
__global__ void k_params(const double* gsum, const uint* gcnt, const uint* gmin,
                         const uint* gmax, double* params) {
    int c = threadIdx.x;
    if (c >= NC) return;
    uint n = gcnt[c];
    double mean[3] = {0, 0, 0}, off[3] = {0, 0, 0}, scale = 50.0;
    if (n) {
        double dn = (double)n;
        double r = 0.0, mn[3];
        for (int d = 0; d < 3; ++d) {
            mean[d] = gsum[c * 3 + d] / dn;
            mn[d] = (double)decF(gmin[c * 3 + d]) - mean[d];
            double mx = (double)decF(gmax[c * 3 + d]) - mean[d];
            double ext = (mx - mn[d]) / (double)FS;
            r = fmax(r, ext);
        }
        double sr = 1.0 / r - 0.01;      // r==0 -> inf -> clamp to 50
        scale = fmin(sr, 50.0);
        for (int d = 0; d < 3; ++d) off[d] = -(mn[d] * scale);
    }
    params[c * 8 + 0] = mean[0]; params[c * 8 + 1] = mean[1]; params[c * 8 + 2] = mean[2];
    params[c * 8 + 3] = scale;
    params[c * 8 + 4] = off[0];  params[c * 8 + 5] = off[1];  params[c * 8 + 6] = off[2];
    params[c * 8 + 7] = 0.0;
}

// ---------- kernel 3: main scatter — 8 threads per pair (one float4 each) ----------
__global__ __launch_bounds__(256) void k_main(const void* cids, const void* pids,
        const float* coords, const float4* feats4, const double* params,
        const uint* flagp, uint* vcnt, float* out, uint* agg) {
    int gid = blockIdx.x * blockDim.x + threadIdx.x;   // < SPAIRS*8 exactly
    int s = gid >> 3, q = gid & 7;
    if (s >= SPAIRS) return;
    uint is64 = *flagp;
    int cid = loadId(cids, s, is64);
    int pid = loadId(pids, s, is64);
    const double* P = params + cid * 8;
    float cx = coords[3 * pid + 0];
    float cy = coords[3 * pid + 1];
    float cz = coords[3 * pid + 2];
    double vx = ((double)cx - P[0]) * P[3] + P[4];
    double vy = ((double)cy - P[1]) * P[3] + P[5];
    double vz = ((double)cz - P[2]) * P[3] + P[6];
    int ix = (int)floor(vx); ix = ix < 0 ? 0 : (ix > FS - 1 ? FS - 1 : ix);
    int iy = (int)floor(vy); iy = iy < 0 ? 0 : (iy > FS - 1 ? FS - 1 : iy);
    int iz = (int)floor(vz); iz = iz < 0 ? 0 : (iz > FS - 1 ? FS - 1 : iz);
    int vid = cid * F3 + (ix * FS + iy) * FS + iz;
    if (q == 0) atomicAdd(&vcnt[vid], 1u);

    float4 f = feats4[(size_t)pid * 8 + q];
    float* o = out + (size_t)vid * 32 + q * 4;
    unsafeAtomicAdd(o + 0, f.x);
    unsafeAtomicAdd(o + 1, f.y);
    unsafeAtomicAdd(o + 2, f.z);
    unsafeAtomicAdd(o + 3, f.w);

    // agg-max: wave-level pre-reduction when all 8 pairs in wave share a cluster
    uint e0 = encF(f.x), e1 = encF(f.y), e2 = encF(f.z), e3 = encF(f.w);
    int lane = threadIdx.x & 63;
    bool uni = __all(cid == __shfl(cid, 0, 64));
    if (uni) {
        #pragma unroll
        for (int st = 8; st < 64; st <<= 1) {
            uint t0 = (uint)__shfl_xor((int)e0, st, 64); e0 = e0 > t0 ? e0 : t0;
            uint t1 = (uint)__shfl_xor((int)e1, st, 64); e1 = e1 > t1 ? e1 : t1;
            uint t2 = (uint)__shfl_xor((int)e2, st, 64); e2 = e2 > t2 ? e2 : t2;
            uint t3 = (uint)__shfl_xor((int)e3, st, 64); e3 = e3 > t3 ? e3 : t3;
        }
        if (lane < 8) {
            uint* a = agg + cid * 32 + lane * 4;
            atomicMax(a + 0, e0); atomicMax(a + 1, e1); atomicMax(a + 2, e2); atomicMax(a + 3, e3);
        }
    } else {
        uint* a = agg + cid * 32 + q * 4;
        atomicMax(a + 0, e0); atomicMax(a + 1, e1); atomicMax(a + 2, e2); atomicMax(a + 3, e3);
    }
}

// ---------- kernel 4: voxel finalize (divide by count; empty voxels stay 0) ----------
__global__ __launch_bounds__(256) void k_voxfin(const uint* vcnt, float4* out4) {
    int idx = blockIdx.x * blockDim.x + threadIdx.x;   // < VOXT*8 exactly
    uint c = vcnt[idx >> 3];
    if (c) {
        float4 t = out4[idx];
        float fc = (float)c;
        t.x /= fc; t.y /= fc; t.z /= fc; t.w /= fc;
        out4[idx] = t;
    }
}

// ---------- kernel 5: agg finalize (decode; untouched -> 0, matches -inf->0) ----------
__global__ void k_aggfin(float* outbase) {
    int i = blockIdx.x * blockDim.x + threadIdx.x;     // < NC*32 exactly
    uint* a = (uint*)(outbase + (size_t)VOXT * 32);
    uint e = a[i];
    float f = (e == 0u) ? 0.0f : decF(e);
    ((float*)a)[i] = f;
}

extern "C" void kernel_launch(void* const* d_in, const int* in_sizes, int n_in,
                              void* d_out, int out_size, void* d_ws, size_t ws_size,
                              hipStream_t stream) {
    const float* feats  = (const float*)d_in[0];
    const float* coords = (const float*)d_in[1];
    const void*  cids   = d_in[2];
    const void*  pids   = d_in[3];
    float* out = (float*)d_out;
    char* ws = (char*)d_ws;

    // ws layout (bytes):
    //   0      uint flag
    //   64     double gsum[256*3]     (6144)
    //   6208   uint  gcnt[256]        (1024)
    //   7232   uint  gmin[256*3]      (3072)
    //   10304  uint  gmax[256*3]      (3072)
    //   13440  double params[256*8]   (16384)
    //   29952  uint  vcnt[VOXT]       (2809856)   -> total 2839808 bytes
    uint*   flag   = (uint*)(ws + 0);
    double* gsum   = (double*)(ws + 64);
    uint*   gcnt   = (uint*)(ws + 6208);
    uint*   gmin   = (uint*)(ws + 7232);
    uint*   gmax   = (uint*)(ws + 10304);
    double* params = (double*)(ws + 13440);
    uint*   vcnt   = (uint*)(ws + 29952);

    // zero: whole output (voxel sums accumulate in place; agg enc-init 0),
    //       ws up through vcnt
    hipMemsetAsync(d_out, 0, (size_t)out_size * sizeof(float), stream);
    hipMemsetAsync(d_ws, 0, (size_t)29952 + (size_t)VOXT * 4, stream);

    k_init<<<4, 256, 0, stream>>>(cids, flag, gmin);
    k_stats<<<1024, 256, 0, stream>>>(cids, pids, coords, flag, gsum, gcnt, gmin, gmax);
    k_params<<<1, 256, 0, stream>>>(gsum, gcnt, gmin, gmax, params);
    k_main<<<(SPAIRS * 8) / 256, 256, 0, stream>>>(cids, pids, coords, (const float4*)feats,
                                                   params, flag, vcnt, out,
                                                   (uint*)(out + (size_t)VOXT * 32));
    k_voxfin<<<(VOXT * 8) / 256, 256, 0, stream>>>(vcnt, (float4*)out);
    k_aggfin<<<(NC * 32) / 256, 256, 0, stream>>>(out);
}

// Round 2
// 208.035 us; speedup vs baseline: 2.0646x; 2.0646x over previous
//
#include <hip/hip_runtime.h>
#include <stdint.h>

typedef unsigned int uint;
typedef unsigned short ushort_t;

#define NPTS 500000
#define NC 256
#define SPAIRS 600000
#define FS 14
#define F3 2744            // 14^3
#define VOXT (NC * F3)     // 702464
#define NGRP 8             // channel groups of 4 (float4)

// ---------- helpers ----------
__device__ __forceinline__ uint encF(float f) {
    uint u = __float_as_uint(f);
    return (u & 0x80000000u) ? ~u : (u | 0x80000000u);
}
__device__ __forceinline__ float decF(uint e) {
    uint u = (e & 0x80000000u) ? (e ^ 0x80000000u) : ~e;
    return __uint_as_float(u);
}
// ids may arrive as int32 (jax x64 off) or int64; runtime flag selects.
__device__ __forceinline__ int loadId(const void* p, int i, uint is64) {
    return is64 ? (int)((const long long*)p)[i] : ((const int*)p)[i];
}

// ---------- kernel 0: init min-encodings + detect id width ----------
__global__ void k_init(const void* cids, uint* flag, uint* gmin) {
    int idx = blockIdx.x * blockDim.x + threadIdx.x;
    if (idx < NC * 3) gmin[idx] = 0xFFFFFFFFu;
    if (idx == 0) {
        // If int64: odd int32 words (high words) are 0. Sorted mid values ~128 != 0.
        const int* p = (const int*)cids;
        int z = 0;
        #pragma unroll
        for (int k = 0; k < 5; ++k) z += (p[300001 + 2 * k] == 0) ? 1 : 0;
        *flag = (z >= 3) ? 1u : 0u;
    }
}

// ---------- kernel 1: per-cluster count / sum(double) / min / max of raw coords ----------
__global__ __launch_bounds__(256) void k_stats(const void* cids, const void* pids,
        const float* coords, const uint* flagp,
        double* gsum, uint* gcnt, uint* gmin, uint* gmax) {
    __shared__ double sSum[NC][3];
    __shared__ uint   sCnt[NC];
    __shared__ uint   sMin[NC][3];
    __shared__ uint   sMax[NC][3];
    int tid = threadIdx.x;
    for (int c = tid; c < NC; c += blockDim.x) {
        sCnt[c] = 0u;
        for (int d = 0; d < 3; ++d) { sSum[c][d] = 0.0; sMin[c][d] = 0xFFFFFFFFu; sMax[c][d] = 0u; }
    }
    __syncthreads();
    uint is64 = *flagp;
    int per = (SPAIRS + gridDim.x - 1) / gridDim.x;
    int start = blockIdx.x * per;
    int end = min(start + per, SPAIRS);
    for (int s = start + tid; s < end; s += blockDim.x) {
        int cid = loadId(cids, s, is64);
        int pid = loadId(pids, s, is64);
        float x = coords[3 * pid + 0];
        float y = coords[3 * pid + 1];
        float z = coords[3 * pid + 2];
        atomicAdd(&sCnt[cid], 1u);
        atomicAdd(&sSum[cid][0], (double)x);
        atomicAdd(&sSum[cid][1], (double)y);
        atomicAdd(&sSum[cid][2], (double)z);
        atomicMin(&sMin[cid][0], encF(x)); atomicMin(&sMin[cid][1], encF(y)); atomicMin(&sMin[cid][2], encF(z));
        atomicMax(&sMax[cid][0], encF(x)); atomicMax(&sMax[cid][1], encF(y)); atomicMax(&sMax[cid][2], encF(z));
    }
    __syncthreads();
    for (int c = tid; c < NC; c += blockDim.x) {
        if (sCnt[c]) {
            atomicAdd(&gcnt[c], sCnt[c]);
            for (int d = 0; d < 3; ++d) {
                atomicAdd(&gsum[c * 3 + d], sSum[c][d]);
                atomicMin(&gmin[c * 3 + d], sMin[c][d]);
                atomicMax(&gmax[c * 3 + d], sMax[c][d]);
            }
        }
    }
}

// ---------- kernel 2: per-cluster mean/scale/offset (double) + pair-range prefix sum ----------
__global__ void k_params(const double* gsum, const uint* gcnt, const uint* gmin,
                         const uint* gmax, double* params, int* coff) {
    int c = threadIdx.x;
    if (c < NC) {
        uint n = gcnt[c];
        double mean[3] = {0, 0, 0}, off[3] = {0, 0, 0}, scale = 50.0;
        if (n) {
            double dn = (double)n;
            double r = 0.0, mn[3];
            for (int d = 0; d < 3; ++d) {
                mean[d] = gsum[c * 3 + d] / dn;
                mn[d] = (double)decF(gmin[c * 3 + d]) - mean[d];
                double mx = (double)decF(gmax[c * 3 + d]) - mean[d];
                double ext = (mx - mn[d]) / (double)FS;
                r = fmax(r, ext);
            }
            double sr = 1.0 / r - 0.01;      // r==0 -> inf -> clamp to 50
            scale = fmin(sr, 50.0);
            for (int d = 0; d < 3; ++d) off[d] = -(mn[d] * scale);
        }
        params[c * 8 + 0] = mean[0]; params[c * 8 + 1] = mean[1]; params[c * 8 + 2] = mean[2];
        params[c * 8 + 3] = scale;
        params[c * 8 + 4] = off[0];  params[c * 8 + 5] = off[1];  params[c * 8 + 6] = off[2];
        params[c * 8 + 7] = 0.0;
    }
    if (threadIdx.x == 0) {
        int acc = 0;
        for (int i = 0; i < NC; ++i) { coff[i] = acc; acc += (int)gcnt[i]; }
        coff[NC] = acc;
    }
}

// ---------- kernel 3: per-pair local voxel id + per-voxel count ----------
__global__ __launch_bounds__(256) void k_vox(const void* cids, const void* pids,
        const float* coords, const double* params, const uint* flagp,
        ushort_t* vidl, uint* vcnt) {
    int s = blockIdx.x * blockDim.x + threadIdx.x;
    if (s >= SPAIRS) return;
    uint is64 = *flagp;
    int cid = loadId(cids, s, is64);
    int pid = loadId(pids, s, is64);
    const double* P = params + cid * 8;
    float cx = coords[3 * pid + 0];
    float cy = coords[3 * pid + 1];
    float cz = coords[3 * pid + 2];
    double vx = ((double)cx - P[0]) * P[3] + P[4];
    double vy = ((double)cy - P[1]) * P[3] + P[5];
    double vz = ((double)cz - P[2]) * P[3] + P[6];
    int ix = (int)floor(vx); ix = ix < 0 ? 0 : (ix > FS - 1 ? FS - 1 : ix);
    int iy = (int)floor(vy); iy = iy < 0 ? 0 : (iy > FS - 1 ? FS - 1 : iy);
    int iz = (int)floor(vz); iz = iz < 0 ? 0 : (iz > FS - 1 ? FS - 1 : iz);
    int v = (ix * FS + iy) * FS + iz;
    vidl[s] = (ushort_t)v;
    atomicAdd(&vcnt[cid * F3 + v], 1u);
}

// ---------- kernel 4: per-(cluster, 4ch-group) LDS accumulate + fused finalize + agg max ----------
// grid = NC*NGRP blocks; swizzled so all 8 groups of a cluster land on one XCD
// (blocks dispatch round-robin over 8 XCDs by blockIdx) -> their 16B/128B-line
// partial writes combine in that XCD's L2 into full lines.
__global__ __launch_bounds__(256) void k_accum(const void* pids, const float4* feats4,
        const ushort_t* vidl, const uint* vcnt, const int* coff, const uint* flagp,
        float* out) {
    __shared__ float acc[4 * F3];     // plane-major [4][F3], 43904 B
    int b = blockIdx.x;
    int x = b & 7;                    // XCD slot
    int k = b >> 3;                   // 0..255
    int c = x * 32 + (k >> 3);        // cluster: 32 consecutive clusters per XCD
    int g = k & 7;                    // channel group (4 channels)
    int tid = threadIdx.x;

    float4* a4 = (float4*)acc;
    #pragma unroll
    for (int i = tid; i < F3; i += 256) a4[i] = make_float4(0.f, 0.f, 0.f, 0.f);
    __syncthreads();

    uint is64 = *flagp;
    int s0 = coff[c], s1 = coff[c + 1];
    float m0 = -INFINITY, m1 = -INFINITY, m2 = -INFINITY, m3 = -INFINITY;
    for (int s = s0 + tid; s < s1; s += 256) {
        int pid = loadId(pids, s, is64);
        int v = (int)vidl[s];
        float4 f = feats4[(size_t)pid * 8 + g];
        atomicAdd(&acc[v],          f.x);
        atomicAdd(&acc[F3 + v],     f.y);
        atomicAdd(&acc[2 * F3 + v], f.z);
        atomicAdd(&acc[3 * F3 + v], f.w);
        m0 = fmaxf(m0, f.x); m1 = fmaxf(m1, f.y); m2 = fmaxf(m2, f.z); m3 = fmaxf(m3, f.w);
    }
    __syncthreads();

    // voxel writeout with fused mean division
    const uint* vc = vcnt + c * F3;
    float4* outv = (float4*)out;      // [vox][8 groups of float4]
    for (int v = tid; v < F3; v += 256) {
        uint n = vc[v];
        float fc = n ? (float)n : 1.0f;
        float4 r;
        r.x = acc[v] / fc;
        r.y = acc[F3 + v] / fc;
        r.z = acc[2 * F3 + v] / fc;
        r.w = acc[3 * F3 + v] / fc;
        outv[(size_t)(c * F3 + v) * 8 + g] = r;
    }
    __syncthreads();

    // agg max: wave butterfly, then cross-wave via LDS (acc is free now)
    #pragma unroll
    for (int st = 1; st < 64; st <<= 1) {
        m0 = fmaxf(m0, __shfl_xor(m0, st, 64));
        m1 = fmaxf(m1, __shfl_xor(m1, st, 64));
        m2 = fmaxf(m2, __shfl_xor(m2, st, 64));
        m3 = fmaxf(m3, __shfl_xor(m3, st, 64));
    }
    int wave = tid >> 6, lane = tid & 63;
    if (lane == 0) { acc[wave * 4 + 0] = m0; acc[wave * 4 + 1] = m1; acc[wave * 4 + 2] = m2; acc[wave * 4 + 3] = m3; }
    __syncthreads();
    if (tid == 0) {
        float r0 = fmaxf(fmaxf(acc[0], acc[4]),  fmaxf(acc[8],  acc[12]));
        float r1 = fmaxf(fmaxf(acc[1], acc[5]),  fmaxf(acc[9],  acc[13]));
        float r2 = fmaxf(fmaxf(acc[2], acc[6]),  fmaxf(acc[10], acc[14]));
        float r3 = fmaxf(fmaxf(acc[3], acc[7]),  fmaxf(acc[11], acc[15]));
        float4 r;
        r.x = (r0 == -INFINITY) ? 0.f : r0;
        r.y = (r1 == -INFINITY) ? 0.f : r1;
        r.z = (r2 == -INFINITY) ? 0.f : r2;
        r.w = (r3 == -INFINITY) ? 0.f : r3;
        *(float4*)(out + (size_t)VOXT * 32 + c * 32 + g * 4) = r;
    }
}

extern "C" void kernel_launch(void* const* d_in, const int* in_sizes, int n_in,
                              void* d_out, int out_size, void* d_ws, size_t ws_size,
                              hipStream_t stream) {
    const float* feats  = (const float*)d_in[0];
    const float* coords = (const float*)d_in[1];
    const void*  cids   = d_in[2];
    const void*  pids   = d_in[3];
    float* out = (float*)d_out;
    char* ws = (char*)d_ws;

    // ws layout (bytes):
    //   0         uint   flag
    //   64        double gsum[256*3]      (6144)
    //   6208      uint   gcnt[256]        (1024)
    //   7232      uint   gmin[256*3]      (3072)
    //   10304     uint   gmax[256*3]      (3072)
    //   13440     double params[256*8]    (16384)
    //   29824     int    coff[257]        (1028 -> pad 1088)
    //   30912     u16    vidl[SPAIRS]     (1200000)
    //   1230912   uint   vcnt[VOXT]       (2809856)  -> total 4040768 bytes
    uint*     flag   = (uint*)(ws + 0);
    double*   gsum   = (double*)(ws + 64);
    uint*     gcnt   = (uint*)(ws + 6208);
    uint*     gmin   = (uint*)(ws + 7232);
    uint*     gmax   = (uint*)(ws + 10304);
    double*   params = (double*)(ws + 13440);
    int*      coff   = (int*)(ws + 29824);
    ushort_t* vidl   = (ushort_t*)(ws + 30912);
    uint*     vcnt   = (uint*)(ws + 1230912);

    // zero the stats region + vcnt (d_out is fully overwritten by k_accum; no memset)
    hipMemsetAsync(d_ws, 0, 30912, stream);
    hipMemsetAsync((void*)vcnt, 0, (size_t)VOXT * 4, stream);

    k_init<<<4, 256, 0, stream>>>(cids, flag, gmin);
    k_stats<<<1024, 256, 0, stream>>>(cids, pids, coords, flag, gsum, gcnt, gmin, gmax);
    k_params<<<1, 256, 0, stream>>>(gsum, gcnt, gmin, gmax, params, coff);
    k_vox<<<(SPAIRS + 255) / 256, 256, 0, stream>>>(cids, pids, coords, params, flag, vidl, vcnt);
    k_accum<<<NC * NGRP, 256, 0, stream>>>(pids, (const float4*)feats, vidl, vcnt, coff, flag, out);
}

// Round 3
// 167.276 us; speedup vs baseline: 2.5676x; 1.2437x over previous
//
#include <hip/hip_runtime.h>
#include <stdint.h>

typedef unsigned int uint;
typedef unsigned short ushort_t;

#define NPTS 500000
#define NC 256
#define SPAIRS 600000
#define FS 14
#define F3 2744            // 14^3
#define VOXT (NC * F3)     // 702464
#define QV 686             // F3/4, voxels per k_out block

// ---------- helpers ----------
__device__ __forceinline__ uint encF(float f) {
    uint u = __float_as_uint(f);
    return (u & 0x80000000u) ? ~u : (u | 0x80000000u);
}
__device__ __forceinline__ float decF(uint e) {
    uint u = (e & 0x80000000u) ? (e ^ 0x80000000u) : ~e;
    return __uint_as_float(u);
}
// ids may arrive as int32 (jax x64 off) or int64; runtime flag selects.
__device__ __forceinline__ int loadId(const void* p, int i, uint is64) {
    return is64 ? (int)((const long long*)p)[i] : ((const int*)p)[i];
}

// ---------- kernel 0: init min-encodings + detect id width ----------
__global__ void k_init(const void* cids, uint* flag, uint* gmin) {
    int idx = blockIdx.x * blockDim.x + threadIdx.x;
    if (idx < NC * 3) gmin[idx] = 0xFFFFFFFFu;
    if (idx == 0) {
        const int* p = (const int*)cids;
        int z = 0;
        #pragma unroll
        for (int k = 0; k < 5; ++k) z += (p[300001 + 2 * k] == 0) ? 1 : 0;
        *flag = (z >= 3) ? 1u : 0u;
    }
}

// ---------- kernel 1: per-cluster count/sum(f64)/min/max — wave-segmented reduce ----------
__global__ __launch_bounds__(256) void k_stats(const void* cids, const void* pids,
        const float* coords, const uint* flagp,
        double* gsum, uint* gcnt, uint* gmin, uint* gmax) {
    __shared__ double sSum[NC][3];
    __shared__ uint   sCnt[NC];
    __shared__ uint   sMin[NC][3];
    __shared__ uint   sMax[NC][3];
    int tid = threadIdx.x;
    for (int c = tid; c < NC; c += 256) {
        sCnt[c] = 0u;
        for (int d = 0; d < 3; ++d) { sSum[c][d] = 0.0; sMin[c][d] = 0xFFFFFFFFu; sMax[c][d] = 0u; }
    }
    __syncthreads();
    uint is64 = *flagp;
    int s = blockIdx.x * 256 + tid;
    bool valid = s < SPAIRS;
    int sc = valid ? s : SPAIRS - 1;
    int cid = loadId(cids, sc, is64);
    int pid = loadId(pids, sc, is64);
    float x = coords[3 * pid + 0];
    float y = coords[3 * pid + 1];
    float z = coords[3 * pid + 2];
    int lane = tid & 63;
    int cid0 = __shfl(cid, 0, 64), cid63 = __shfl(cid, 63, 64);
    if (cid0 == cid63) {
        // whole wave one cluster (common: sorted ids, ~2344 pairs/cluster)
        uint nval = (uint)__popcll(__ballot(valid));
        double dx = valid ? (double)x : 0.0;
        double dy = valid ? (double)y : 0.0;
        double dz = valid ? (double)z : 0.0;
        float mnx = valid ? x : INFINITY,  mny = valid ? y : INFINITY,  mnz = valid ? z : INFINITY;
        float mxx = valid ? x : -INFINITY, mxy = valid ? y : -INFINITY, mxz = valid ? z : -INFINITY;
        #pragma unroll
        for (int st = 1; st < 64; st <<= 1) {
            dx += __shfl_xor(dx, st, 64);
            dy += __shfl_xor(dy, st, 64);
            dz += __shfl_xor(dz, st, 64);
            mnx = fminf(mnx, __shfl_xor(mnx, st, 64));
            mny = fminf(mny, __shfl_xor(mny, st, 64));
            mnz = fminf(mnz, __shfl_xor(mnz, st, 64));
            mxx = fmaxf(mxx, __shfl_xor(mxx, st, 64));
            mxy = fmaxf(mxy, __shfl_xor(mxy, st, 64));
            mxz = fmaxf(mxz, __shfl_xor(mxz, st, 64));
        }
        if (lane == 0 && nval) {
            atomicAdd(&sCnt[cid0], nval);
            unsafeAtomicAdd(&sSum[cid0][0], dx);
            unsafeAtomicAdd(&sSum[cid0][1], dy);
            unsafeAtomicAdd(&sSum[cid0][2], dz);
            atomicMin(&sMin[cid0][0], encF(mnx)); atomicMin(&sMin[cid0][1], encF(mny)); atomicMin(&sMin[cid0][2], encF(mnz));
            atomicMax(&sMax[cid0][0], encF(mxx)); atomicMax(&sMax[cid0][1], encF(mxy)); atomicMax(&sMax[cid0][2], encF(mxz));
        }
    } else if (valid) {
        // cluster-boundary wave (<=255 of 9376): per-lane fallback
        atomicAdd(&sCnt[cid], 1u);
        unsafeAtomicAdd(&sSum[cid][0], (double)x);
        unsafeAtomicAdd(&sSum[cid][1], (double)y);
        unsafeAtomicAdd(&sSum[cid][2], (double)z);
        atomicMin(&sMin[cid][0], encF(x)); atomicMin(&sMin[cid][1], encF(y)); atomicMin(&sMin[cid][2], encF(z));
        atomicMax(&sMax[cid][0], encF(x)); atomicMax(&sMax[cid][1], encF(y)); atomicMax(&sMax[cid][2], encF(z));
    }
    __syncthreads();
    for (int c = tid; c < NC; c += 256) {
        if (sCnt[c]) {
            atomicAdd(&gcnt[c], sCnt[c]);
            for (int d = 0; d < 3; ++d) {
                unsafeAtomicAdd(&gsum[c * 3 + d], sSum[c][d]);
                atomicMin(&gmin[c * 3 + d], sMin[c][d]);
                atomicMax(&gmax[c * 3 + d], sMax[c][d]);
            }
        }
    }
}

// ---------- kernel 2: per-cluster mean/scale/offset (double) + pair-range prefix ----------
__global__ void k_params(const double* gsum, const uint* gcnt, const uint* gmin,
                         const uint* gmax, double* params, int* coff) {
    int c = threadIdx.x;
    if (c < NC) {
        uint n = gcnt[c];
        double mean[3] = {0, 0, 0}, off[3] = {0, 0, 0}, scale = 50.0;
        if (n) {
            double dn = (double)n;
            double r = 0.0, mn[3];
            for (int d = 0; d < 3; ++d) {
                mean[d] = gsum[c * 3 + d] / dn;
                mn[d] = (double)decF(gmin[c * 3 + d]) - mean[d];
                double mx = (double)decF(gmax[c * 3 + d]) - mean[d];
                double ext = (mx - mn[d]) / (double)FS;
                r = fmax(r, ext);
            }
            double sr = 1.0 / r - 0.01;      // r==0 -> inf -> clamp to 50
            scale = fmin(sr, 50.0);
            for (int d = 0; d < 3; ++d) off[d] = -(mn[d] * scale);
        }
        params[c * 8 + 0] = mean[0]; params[c * 8 + 1] = mean[1]; params[c * 8 + 2] = mean[2];
        params[c * 8 + 3] = scale;
        params[c * 8 + 4] = off[0];  params[c * 8 + 5] = off[1];  params[c * 8 + 6] = off[2];
        params[c * 8 + 7] = 0.0;
    }
    if (threadIdx.x == 0) {
        int acc = 0;
        for (int i = 0; i < NC; ++i) { coff[i] = acc; acc += (int)gcnt[i]; }
        coff[NC] = acc;
    }
}

// ---------- kernel 3: per-pair local voxel id + per-voxel count (into vptr) ----------
__global__ __launch_bounds__(256) void k_vox(const void* cids, const void* pids,
        const float* coords, const double* params, const uint* flagp,
        ushort_t* vidl, uint* vptr) {
    int s = blockIdx.x * blockDim.x + threadIdx.x;
    if (s >= SPAIRS) return;
    uint is64 = *flagp;
    int cid = loadId(cids, s, is64);
    int pid = loadId(pids, s, is64);
    const double* P = params + cid * 8;
    float cx = coords[3 * pid + 0];
    float cy = coords[3 * pid + 1];
    float cz = coords[3 * pid + 2];
    double vx = ((double)cx - P[0]) * P[3] + P[4];
    double vy = ((double)cy - P[1]) * P[3] + P[5];
    double vz = ((double)cz - P[2]) * P[3] + P[6];
    int ix = (int)floor(vx); ix = ix < 0 ? 0 : (ix > FS - 1 ? FS - 1 : ix);
    int iy = (int)floor(vy); iy = iy < 0 ? 0 : (iy > FS - 1 ? FS - 1 : iy);
    int iz = (int)floor(vz); iz = iz < 0 ? 0 : (iz > FS - 1 ? FS - 1 : iz);
    int v = (ix * FS + iy) * FS + iz;
    vidl[s] = (ushort_t)v;
    atomicAdd(&vptr[cid * F3 + v], 1u);
}

// ---------- kernel 4: per-cluster in-place exclusive scan of vptr (+ coff base) ----------
__global__ __launch_bounds__(256) void k_scan(const int* coff, uint* vptr) {
    __shared__ uint wsum[4];
    int c = blockIdx.x, t = threadIdx.x;
    uint* base = vptr + c * F3;
    int b0 = t * 11;                 // 11*256 = 2816 >= F3
    uint v[11];
    uint s = 0;
    #pragma unroll
    for (int i = 0; i < 11; ++i) {
        int idx = b0 + i;
        uint x = (idx < F3) ? base[idx] : 0u;
        v[i] = s;
        s += x;
    }
    uint run = s;
    #pragma unroll
    for (int d = 1; d < 64; d <<= 1) {
        uint y = __shfl_up(run, d, 64);
        if ((t & 63) >= d) run += y;
    }
    int w = t >> 6;
    if ((t & 63) == 63) wsum[w] = run;
    __syncthreads();
    uint woff = 0;
    #pragma unroll
    for (int i = 0; i < 4; ++i) if (i < w) woff += wsum[i];
    uint excl = run - s + woff + (uint)coff[c];
    #pragma unroll
    for (int i = 0; i < 11; ++i) {
        int idx = b0 + i;
        if (idx < F3) base[idx] = excl + v[i];
    }
}

// ---------- kernel 5: counting-sort scatter: spid = pair pids sorted by (cluster,voxel) ----------
__global__ __launch_bounds__(256) void k_scatter(const void* cids, const void* pids,
        const ushort_t* vidl, const uint* flagp, uint* vptr, int* spid) {
    int s = blockIdx.x * blockDim.x + threadIdx.x;
    if (s >= SPAIRS) return;
    uint is64 = *flagp;
    int cid = loadId(cids, s, is64);
    int pid = loadId(pids, s, is64);
    int vid = cid * F3 + (int)vidl[s];
    uint pos = atomicAdd(&vptr[vid], 1u);   // vptr becomes "end" per voxel
    spid[pos] = pid;
}

// ---------- kernel 6: per-voxel gather-sum + mean + agg-max, streaming writes ----------
// grid = NC*4 blocks; blockIdx swizzled so all 4 blocks of a cluster (and 32
// consecutive clusters) land on one XCD for L2 locality of vptr/spid/out lines.
__global__ __launch_bounds__(256) void k_out(const float4* feats4, const uint* vptr,
        const int* spid, float* out, uint* agg) {
    __shared__ float red[4][32];
    int b = blockIdx.x;
    int xcd = b & 7, r = b >> 3;
    int c = xcd * 32 + (r >> 2);     // cluster
    int p = r & 3;                   // quarter
    int t = threadIdx.x;

    float4 mx[8];
    #pragma unroll
    for (int g = 0; g < 8; ++g) mx[g] = make_float4(-INFINITY, -INFINITY, -INFINITY, -INFINITY);

    int vend_q = (p + 1) * QV;
    for (int v = p * QV + t; v < vend_q; v += 256) {
        int vid = c * F3 + v;
        uint end = vptr[vid];
        uint start = (vid == 0) ? 0u : vptr[vid - 1];
        float4 a[8];
        #pragma unroll
        for (int g = 0; g < 8; ++g) a[g] = make_float4(0.f, 0.f, 0.f, 0.f);
        for (uint q = start; q < end; ++q) {
            const float4* fr = feats4 + (size_t)spid[q] * 8;
            #pragma unroll
            for (int g = 0; g < 8; ++g) {
                float4 f = fr[g];
                a[g].x += f.x; a[g].y += f.y; a[g].z += f.z; a[g].w += f.w;
                mx[g].x = fmaxf(mx[g].x, f.x); mx[g].y = fmaxf(mx[g].y, f.y);
                mx[g].z = fmaxf(mx[g].z, f.z); mx[g].w = fmaxf(mx[g].w, f.w);
            }
        }
        uint cnt = end - start;
        float fc = (float)(cnt ? cnt : 1u);
        float4* o = (float4*)(out + (size_t)vid * 32);
        #pragma unroll
        for (int g = 0; g < 8; ++g) {
            float4 rr;
            rr.x = a[g].x / fc; rr.y = a[g].y / fc; rr.z = a[g].z / fc; rr.w = a[g].w / fc;
            o[g] = rr;
        }
    }

    // block-wide agg max over the 32 channels
    #pragma unroll
    for (int g = 0; g < 8; ++g) {
        #pragma unroll
        for (int st = 1; st < 64; st <<= 1) {
            mx[g].x = fmaxf(mx[g].x, __shfl_xor(mx[g].x, st, 64));
            mx[g].y = fmaxf(mx[g].y, __shfl_xor(mx[g].y, st, 64));
            mx[g].z = fmaxf(mx[g].z, __shfl_xor(mx[g].z, st, 64));
            mx[g].w = fmaxf(mx[g].w, __shfl_xor(mx[g].w, st, 64));
        }
    }
    int wave = t >> 6, lane = t & 63;
    if (lane == 0) {
        #pragma unroll
        for (int g = 0; g < 8; ++g) {
            red[wave][g * 4 + 0] = mx[g].x; red[wave][g * 4 + 1] = mx[g].y;
            red[wave][g * 4 + 2] = mx[g].z; red[wave][g * 4 + 3] = mx[g].w;
        }
    }
    __syncthreads();
    if (t < 32) {
        float m = fmaxf(fmaxf(red[0][t], red[1][t]), fmaxf(red[2][t], red[3][t]));
        if (m != -INFINITY) atomicMax(&agg[c * 32 + t], encF(m));
    }
}

// ---------- kernel 7: agg finalize (decode; untouched/neginf -> 0) ----------
__global__ void k_aggfin(float* outbase) {
    int i = blockIdx.x * blockDim.x + threadIdx.x;     // < NC*32 exactly
    uint* a = (uint*)(outbase + (size_t)VOXT * 32);
    uint e = a[i];
    float f = decF(e);
    if (e == 0u || f == -INFINITY) f = 0.0f;
    ((float*)a)[i] = f;
}

extern "C" void kernel_launch(void* const* d_in, const int* in_sizes, int n_in,
                              void* d_out, int out_size, void* d_ws, size_t ws_size,
                              hipStream_t stream) {
    const float* feats  = (const float*)d_in[0];
    const float* coords = (const float*)d_in[1];
    const void*  cids   = d_in[2];
    const void*  pids   = d_in[3];
    float* out = (float*)d_out;
    char* ws = (char*)d_ws;

    // ws layout (bytes):
    //   0         uint   flag
    //   64        double gsum[256*3]      (6144)
    //   6208      uint   gcnt[256]        (1024)
    //   7232      uint   gmin[256*3]      (3072)
    //   10304     uint   gmax[256*3]      (3072)
    //   13440     double params[256*8]    (16384)
    //   29824     int    coff[257]        (1028 -> pad to 30912)
    //   30912     u16    vidl[SPAIRS]     (1200000)
    //   1230912   uint   vptr[VOXT]       (2809856)   counts -> scan -> ends
    //   4040768   int    spid[SPAIRS]     (2400000)   -> total 6440768 bytes
    uint*     flag   = (uint*)(ws + 0);
    double*   gsum   = (double*)(ws + 64);
    uint*     gcnt   = (uint*)(ws + 6208);
    uint*     gmin   = (uint*)(ws + 7232);
    uint*     gmax   = (uint*)(ws + 10304);
    double*   params = (double*)(ws + 13440);
    int*      coff   = (int*)(ws + 29824);
    ushort_t* vidl   = (ushort_t*)(ws + 30912);
    uint*     vptr   = (uint*)(ws + 1230912);
    int*      spid   = (int*)(ws + 4040768);

    hipMemsetAsync(d_ws, 0, 30912, stream);                            // stats region
    hipMemsetAsync((void*)vptr, 0, (size_t)VOXT * 4, stream);          // voxel counts
    hipMemsetAsync((void*)(out + (size_t)VOXT * 32), 0, NC * 32 * 4, stream);  // agg encodings

    int nb = (SPAIRS + 255) / 256;   // 2344
    k_init<<<4, 256, 0, stream>>>(cids, flag, gmin);
    k_stats<<<nb, 256, 0, stream>>>(cids, pids, coords, flag, gsum, gcnt, gmin, gmax);
    k_params<<<1, 256, 0, stream>>>(gsum, gcnt, gmin, gmax, params, coff);
    k_vox<<<nb, 256, 0, stream>>>(cids, pids, coords, params, flag, vidl, vptr);
    k_scan<<<NC, 256, 0, stream>>>(coff, vptr);
    k_scatter<<<nb, 256, 0, stream>>>(cids, pids, vidl, flag, vptr, spid);
    k_out<<<NC * 4, 256, 0, stream>>>((const float4*)feats, vptr, spid, out,
                                      (uint*)(out + (size_t)VOXT * 32));
    k_aggfin<<<(NC * 32) / 256, 256, 0, stream>>>(out);
}

// Round 4
// 143.012 us; speedup vs baseline: 3.0033x; 1.1697x over previous
//
#include <hip/hip_runtime.h>
#include <stdint.h>

typedef unsigned int uint;
typedef unsigned short ushort_t;

#define NPTS 500000
#define NC 256
#define SPAIRS 600000
#define FS 14
#define F3 2744            // 14^3
#define VOXT (NC * F3)     // 702464
#define QV8 343            // F3/8, voxels per k_out block

// ---------- helpers ----------
__device__ __forceinline__ uint encF(float f) {
    uint u = __float_as_uint(f);
    return (u & 0x80000000u) ? ~u : (u | 0x80000000u);
}
__device__ __forceinline__ float decF(uint e) {
    uint u = (e & 0x80000000u) ? (e ^ 0x80000000u) : ~e;
    return __uint_as_float(u);
}
// ids may arrive as int32 (jax x64 off) or int64. Sorted cids: mid values ~128,
// so for int64 the odd int32 words (high) are 0; for int32 they're nonzero.
__device__ __forceinline__ uint detect64(const void* cids) {
    const int* p = (const int*)cids;
    int z = 0;
    #pragma unroll
    for (int k = 0; k < 5; ++k) z += (p[300001 + 2 * k] == 0) ? 1 : 0;
    return (z >= 3) ? 1u : 0u;
}
__device__ __forceinline__ int loadId(const void* p, int i, uint is64) {
    return is64 ? (int)((const long long*)p)[i] : ((const int*)p)[i];
}

// ---------- kernel 1: per-cluster count/sum(f64)/min/max — wave-segmented reduce ----------
__global__ __launch_bounds__(256) void k_stats(const void* cids, const void* pids,
        const float* coords,
        double* gsum, uint* gcnt, uint* gmin, uint* gmax) {
    __shared__ double sSum[NC][3];
    __shared__ uint   sCnt[NC];
    __shared__ uint   sMin[NC][3];
    __shared__ uint   sMax[NC][3];
    int tid = threadIdx.x;
    for (int c = tid; c < NC; c += 256) {
        sCnt[c] = 0u;
        for (int d = 0; d < 3; ++d) { sSum[c][d] = 0.0; sMin[c][d] = 0xFFFFFFFFu; sMax[c][d] = 0u; }
    }
    __syncthreads();
    uint is64 = detect64(cids);
    int s = blockIdx.x * 256 + tid;
    bool valid = s < SPAIRS;
    int sc = valid ? s : SPAIRS - 1;
    int cid = loadId(cids, sc, is64);
    int pid = loadId(pids, sc, is64);
    float x = coords[3 * pid + 0];
    float y = coords[3 * pid + 1];
    float z = coords[3 * pid + 2];
    int lane = tid & 63;
    int cid0 = __shfl(cid, 0, 64), cid63 = __shfl(cid, 63, 64);
    if (cid0 == cid63) {
        // whole wave one cluster (common: sorted ids, ~2344 pairs/cluster)
        uint nval = (uint)__popcll(__ballot(valid));
        double dx = valid ? (double)x : 0.0;
        double dy = valid ? (double)y : 0.0;
        double dz = valid ? (double)z : 0.0;
        float mnx = valid ? x : INFINITY,  mny = valid ? y : INFINITY,  mnz = valid ? z : INFINITY;
        float mxx = valid ? x : -INFINITY, mxy = valid ? y : -INFINITY, mxz = valid ? z : -INFINITY;
        #pragma unroll
        for (int st = 1; st < 64; st <<= 1) {
            dx += __shfl_xor(dx, st, 64);
            dy += __shfl_xor(dy, st, 64);
            dz += __shfl_xor(dz, st, 64);
            mnx = fminf(mnx, __shfl_xor(mnx, st, 64));
            mny = fminf(mny, __shfl_xor(mny, st, 64));
            mnz = fminf(mnz, __shfl_xor(mnz, st, 64));
            mxx = fmaxf(mxx, __shfl_xor(mxx, st, 64));
            mxy = fmaxf(mxy, __shfl_xor(mxy, st, 64));
            mxz = fmaxf(mxz, __shfl_xor(mxz, st, 64));
        }
        if (lane == 0 && nval) {
            atomicAdd(&sCnt[cid0], nval);
            unsafeAtomicAdd(&sSum[cid0][0], dx);
            unsafeAtomicAdd(&sSum[cid0][1], dy);
            unsafeAtomicAdd(&sSum[cid0][2], dz);
            atomicMin(&sMin[cid0][0], encF(mnx)); atomicMin(&sMin[cid0][1], encF(mny)); atomicMin(&sMin[cid0][2], encF(mnz));
            atomicMax(&sMax[cid0][0], encF(mxx)); atomicMax(&sMax[cid0][1], encF(mxy)); atomicMax(&sMax[cid0][2], encF(mxz));
        }
    } else if (valid) {
        // cluster-boundary wave (<=255 of 9376): per-lane fallback
        atomicAdd(&sCnt[cid], 1u);
        unsafeAtomicAdd(&sSum[cid][0], (double)x);
        unsafeAtomicAdd(&sSum[cid][1], (double)y);
        unsafeAtomicAdd(&sSum[cid][2], (double)z);
        atomicMin(&sMin[cid][0], encF(x)); atomicMin(&sMin[cid][1], encF(y)); atomicMin(&sMin[cid][2], encF(z));
        atomicMax(&sMax[cid][0], encF(x)); atomicMax(&sMax[cid][1], encF(y)); atomicMax(&sMax[cid][2], encF(z));
    }
    __syncthreads();
    for (int c = tid; c < NC; c += 256) {
        if (sCnt[c]) {
            atomicAdd(&gcnt[c], sCnt[c]);
            for (int d = 0; d < 3; ++d) {
                unsafeAtomicAdd(&gsum[c * 3 + d], sSum[c][d]);
                atomicMin(&gmin[c * 3 + d], sMin[c][d]);
                atomicMax(&gmax[c * 3 + d], sMax[c][d]);
            }
        }
    }
}

// ---------- kernel 2: per-cluster mean/scale/offset (double) + parallel prefix for coff ----------
__global__ void k_params(const double* gsum, const uint* gcnt, const uint* gmin,
                         const uint* gmax, double* params, int* coff) {
    __shared__ uint wsum[4];
    int c = threadIdx.x;                 // exactly 256 threads
    uint n = gcnt[c];
    double mean[3] = {0, 0, 0}, off[3] = {0, 0, 0}, scale = 50.0;
    if (n) {
        double dn = (double)n;
        double r = 0.0, mn[3];
        for (int d = 0; d < 3; ++d) {
            mean[d] = gsum[c * 3 + d] / dn;
            mn[d] = (double)decF(gmin[c * 3 + d]) - mean[d];
            double mx = (double)decF(gmax[c * 3 + d]) - mean[d];
            double ext = (mx - mn[d]) / (double)FS;
            r = fmax(r, ext);
        }
        double sr = 1.0 / r - 0.01;      // r==0 -> inf -> clamp to 50
        scale = fmin(sr, 50.0);
        for (int d = 0; d < 3; ++d) off[d] = -(mn[d] * scale);
    }
    params[c * 8 + 0] = mean[0]; params[c * 8 + 1] = mean[1]; params[c * 8 + 2] = mean[2];
    params[c * 8 + 3] = scale;
    params[c * 8 + 4] = off[0];  params[c * 8 + 5] = off[1];  params[c * 8 + 6] = off[2];
    params[c * 8 + 7] = 0.0;

    // exclusive prefix of gcnt -> coff (4-wave scan)
    uint incl = n;
    #pragma unroll
    for (int d = 1; d < 64; d <<= 1) {
        uint y = __shfl_up(incl, d, 64);
        if ((c & 63) >= d) incl += y;
    }
    int w = c >> 6;
    if ((c & 63) == 63) wsum[w] = incl;
    __syncthreads();
    uint woff = 0;
    #pragma unroll
    for (int i = 0; i < 4; ++i) if (i < w) woff += wsum[i];
    coff[c] = (int)(incl - n + woff);
    if (c == 255) coff[NC] = (int)(incl + woff);
}

// ---------- kernel 3: per-pair local voxel id + per-voxel count (into vptr) ----------
__global__ __launch_bounds__(256) void k_vox(const void* cids, const void* pids,
        const float* coords, const double* params,
        ushort_t* vidl, uint* vptr) {
    int s = blockIdx.x * blockDim.x + threadIdx.x;
    if (s >= SPAIRS) return;
    uint is64 = detect64(cids);
    int cid = loadId(cids, s, is64);
    int pid = loadId(pids, s, is64);
    const double* P = params + cid * 8;
    float cx = coords[3 * pid + 0];
    float cy = coords[3 * pid + 1];
    float cz = coords[3 * pid + 2];
    double vx = ((double)cx - P[0]) * P[3] + P[4];
    double vy = ((double)cy - P[1]) * P[3] + P[5];
    double vz = ((double)cz - P[2]) * P[3] + P[6];
    int ix = (int)floor(vx); ix = ix < 0 ? 0 : (ix > FS - 1 ? FS - 1 : ix);
    int iy = (int)floor(vy); iy = iy < 0 ? 0 : (iy > FS - 1 ? FS - 1 : iy);
    int iz = (int)floor(vz); iz = iz < 0 ? 0 : (iz > FS - 1 ? FS - 1 : iz);
    int v = (ix * FS + iy) * FS + iz;
    vidl[s] = (ushort_t)v;
    atomicAdd(&vptr[cid * F3 + v], 1u);
}

// ---------- kernel 4: per-cluster in-place exclusive scan of vptr (+ coff base) ----------
__global__ __launch_bounds__(256) void k_scan(const int* coff, uint* vptr) {
    __shared__ uint wsum[4];
    int c = blockIdx.x, t = threadIdx.x;
    uint* base = vptr + c * F3;
    int b0 = t * 11;                 // 11*256 = 2816 >= F3
    uint v[11];
    uint s = 0;
    #pragma unroll
    for (int i = 0; i < 11; ++i) {
        int idx = b0 + i;
        uint x = (idx < F3) ? base[idx] : 0u;
        v[i] = s;
        s += x;
    }
    uint run = s;
    #pragma unroll
    for (int d = 1; d < 64; d <<= 1) {
        uint y = __shfl_up(run, d, 64);
        if ((t & 63) >= d) run += y;
    }
    int w = t >> 6;
    if ((t & 63) == 63) wsum[w] = run;
    __syncthreads();
    uint woff = 0;
    #pragma unroll
    for (int i = 0; i < 4; ++i) if (i < w) woff += wsum[i];
    uint excl = run - s + woff + (uint)coff[c];
    #pragma unroll
    for (int i = 0; i < 11; ++i) {
        int idx = b0 + i;
        if (idx < F3) base[idx] = excl + v[i];
    }
}

// ---------- kernel 5: counting-sort scatter: spid = pair pids sorted by (cluster,voxel) ----------
__global__ __launch_bounds__(256) void k_scatter(const void* cids, const void* pids,
        const ushort_t* vidl, uint* vptr, int* spid) {
    int s = blockIdx.x * blockDim.x + threadIdx.x;
    if (s >= SPAIRS) return;
    uint is64 = detect64(cids);
    int cid = loadId(cids, s, is64);
    int pid = loadId(pids, s, is64);
    int vid = cid * F3 + (int)vidl[s];
    uint pos = atomicAdd(&vptr[vid], 1u);   // vptr becomes "end" per voxel
    spid[pos] = pid;
}

// ---------- kernel 6: per-voxel gather-sum + mean + agg-max, streaming writes ----------
// grid = NC*8 blocks (8192 waves = full device); blockIdx swizzled so the 8
// blocks of a cluster (and 32 consecutive clusters) land on one XCD.
__global__ __launch_bounds__(256) void k_out(const float4* feats4, const uint* vptr,
        const int* spid, float* out, uint* agg) {
    __shared__ float red[4][32];
    int b = blockIdx.x;
    int xcd = b & 7, r = b >> 3;
    int c = xcd * 32 + (r >> 3);     // cluster
    int p = r & 7;                   // eighth
    int t = threadIdx.x;

    float4 mx[8];
    #pragma unroll
    for (int g = 0; g < 8; ++g) mx[g] = make_float4(-INFINITY, -INFINITY, -INFINITY, -INFINITY);

    int vend_q = (p + 1) * QV8;
    for (int v = p * QV8 + t; v < vend_q; v += 256) {
        int vid = c * F3 + v;
        uint end = vptr[vid];
        uint start = (vid == 0) ? 0u : vptr[vid - 1];
        float4 a[8];
        #pragma unroll
        for (int g = 0; g < 8; ++g) a[g] = make_float4(0.f, 0.f, 0.f, 0.f);
        for (uint q = start; q < end; ++q) {
            const float4* fr = feats4 + (size_t)spid[q] * 8;
            #pragma unroll
            for (int g = 0; g < 8; ++g) {
                float4 f = fr[g];
                a[g].x += f.x; a[g].y += f.y; a[g].z += f.z; a[g].w += f.w;
                mx[g].x = fmaxf(mx[g].x, f.x); mx[g].y = fmaxf(mx[g].y, f.y);
                mx[g].z = fmaxf(mx[g].z, f.z); mx[g].w = fmaxf(mx[g].w, f.w);
            }
        }
        uint cnt = end - start;
        float inv = 1.0f / (float)(cnt ? cnt : 1u);   // 1 divide, 32 muls
        float4* o = (float4*)(out + (size_t)vid * 32);
        #pragma unroll
        for (int g = 0; g < 8; ++g) {
            float4 rr;
            rr.x = a[g].x * inv; rr.y = a[g].y * inv; rr.z = a[g].z * inv; rr.w = a[g].w * inv;
            o[g] = rr;
        }
    }

    // block-wide agg max over the 32 channels
    #pragma unroll
    for (int g = 0; g < 8; ++g) {
        #pragma unroll
        for (int st = 1; st < 64; st <<= 1) {
            mx[g].x = fmaxf(mx[g].x, __shfl_xor(mx[g].x, st, 64));
            mx[g].y = fmaxf(mx[g].y, __shfl_xor(mx[g].y, st, 64));
            mx[g].z = fmaxf(mx[g].z, __shfl_xor(mx[g].z, st, 64));
            mx[g].w = fmaxf(mx[g].w, __shfl_xor(mx[g].w, st, 64));
        }
    }
    int wave = t >> 6, lane = t & 63;
    if (lane == 0) {
        #pragma unroll
        for (int g = 0; g < 8; ++g) {
            red[wave][g * 4 + 0] = mx[g].x; red[wave][g * 4 + 1] = mx[g].y;
            red[wave][g * 4 + 2] = mx[g].z; red[wave][g * 4 + 3] = mx[g].w;
        }
    }
    __syncthreads();
    if (t < 32) {
        float m = fmaxf(fmaxf(red[0][t], red[1][t]), fmaxf(red[2][t], red[3][t]));
        if (m != -INFINITY) atomicMax(&agg[c * 32 + t], encF(m));
    }
}

// ---------- kernel 7: agg finalize (decode; untouched/neginf -> 0) ----------
__global__ void k_aggfin(float* outbase) {
    int i = blockIdx.x * blockDim.x + threadIdx.x;     // < NC*32 exactly
    uint* a = (uint*)(outbase + (size_t)VOXT * 32);
    uint e = a[i];
    float f = decF(e);
    if (e == 0u || f == -INFINITY) f = 0.0f;
    ((float*)a)[i] = f;
}

extern "C" void kernel_launch(void* const* d_in, const int* in_sizes, int n_in,
                              void* d_out, int out_size, void* d_ws, size_t ws_size,
                              hipStream_t stream) {
    const float* feats  = (const float*)d_in[0];
    const float* coords = (const float*)d_in[1];
    const void*  cids   = d_in[2];
    const void*  pids   = d_in[3];
    float* out = (float*)d_out;
    char* ws = (char*)d_ws;

    // ws layout (bytes) — zeroed region is one contiguous block:
    //   0        double gsum[256*3]      (6144)   } zero
    //   6144     uint   gcnt[256]        (1024)   } zero
    //   7168     uint   gmax[256*3]      (3072)   } zero
    //   10240    uint   vptr[VOXT]       (2809856)} zero   -> 2820096
    //   2820096  uint   gmin[256*3]      (3072)   0xFF     -> 2823168
    //   2823168  double params[256*8]    (16384)  written  -> 2839552
    //   2839552  int    coff[257]        (1028+pad)        -> 2840640
    //   2840640  u16    vidl[SPAIRS]     (1200000)         -> 4040640
    //   4040640  int    spid[SPAIRS]     (2400000)         -> 6440640
    double*   gsum   = (double*)(ws + 0);
    uint*     gcnt   = (uint*)(ws + 6144);
    uint*     gmax   = (uint*)(ws + 7168);
    uint*     vptr   = (uint*)(ws + 10240);
    uint*     gmin   = (uint*)(ws + 2820096);
    double*   params = (double*)(ws + 2823168);
    int*      coff   = (int*)(ws + 2839552);
    ushort_t* vidl   = (ushort_t*)(ws + 2840640);
    int*      spid   = (int*)(ws + 4040640);

    hipMemsetAsync(ws, 0, 2820096, stream);                                    // gsum..vptr
    hipMemsetAsync((void*)gmin, 0xFF, 3072, stream);                           // gmin = +max enc
    hipMemsetAsync((void*)(out + (size_t)VOXT * 32), 0, NC * 32 * 4, stream);  // agg encodings

    int nb = (SPAIRS + 255) / 256;   // 2344
    k_stats<<<nb, 256, 0, stream>>>(cids, pids, coords, gsum, gcnt, gmin, gmax);
    k_params<<<1, 256, 0, stream>>>(gsum, gcnt, gmin, gmax, params, coff);
    k_vox<<<nb, 256, 0, stream>>>(cids, pids, coords, params, vidl, vptr);
    k_scan<<<NC, 256, 0, stream>>>(coff, vptr);
    k_scatter<<<nb, 256, 0, stream>>>(cids, pids, vidl, vptr, spid);
    k_out<<<NC * 8, 256, 0, stream>>>((const float4*)feats, vptr, spid, out,
                                      (uint*)(out + (size_t)VOXT * 32));
    k_aggfin<<<(NC * 32) / 256, 256, 0, stream>>>(out);
}